// Round 5
// baseline (70.306 us; speedup 1.0000x reference)
//
#include <hip/hip_runtime.h>

#define N_TOK 8192
#define D_DIM 1024
#define E_NUM 8
#define D4 (D_DIM / 4)
#define SCAN_BLOCKS 32          // N_TOK / 256
#define ROWS_PER_BLOCK 8
#define GATHER_BLOCKS (E_NUM * N_TOK / ROWS_PER_BLOCK)   // 8192

typedef unsigned long long u64;
typedef float f32x4 __attribute__((ext_vector_type(4)));

// Workspace layout:
//   bsum[32]      ulonglong2 : packed per-block expert counts (512 B)
//   srcmap[E*N]   int2       : {token n or -1, scale bits}    (512 KB)
// Packing: .x = experts 0..3, .y = experts 4..7, 16-bit fields each.

// K1: per-block packed reduction of hot_mask. 32 blocks x 256 threads.
__global__ __launch_bounds__(256) void reduce_kernel(
    const int4* __restrict__ mask4,       // hot_mask as [N][2] int4
    ulonglong2* __restrict__ bsum)        // [SCAN_BLOCKS]
{
    const int t = threadIdx.x;
    const int n = blockIdx.x * 256 + t;

    const int4 a = mask4[(size_t)n * 2];
    const int4 b = mask4[(size_t)n * 2 + 1];
    u64 lo = (u64)a.x | ((u64)a.y << 16) | ((u64)a.z << 32) | ((u64)a.w << 48);
    u64 hi = (u64)b.x | ((u64)b.y << 16) | ((u64)b.z << 32) | ((u64)b.w << 48);

    __shared__ u64 slo[256], shi[256];
    slo[t] = lo; shi[t] = hi;
    __syncthreads();

    for (int off = 128; off > 0; off >>= 1) {
        if (t < off) { slo[t] += slo[t + off]; shi[t] += shi[t + off]; }
        __syncthreads();
    }

    if (t == 0) {
        ulonglong2 s; s.x = slo[0]; s.y = shi[0];
        bsum[blockIdx.x] = s;
    }
}

// K2: finalize. 32 blocks x 256 threads, 1 token/thread.
// Local packed scan + bsum prefix -> global ranks; builds srcmap, tags, counts.
__global__ __launch_bounds__(256) void finalize_kernel(
    const int4* __restrict__ mask4,
    const ulonglong2* __restrict__ bsum,
    const float4* __restrict__ score4,    // score as [N][2] float4
    int2* __restrict__ srcmap,            // [E*N] (ws)
    float* __restrict__ out_tags,         // [E, N]
    float* __restrict__ out_counts)       // [E]
{
    const int bid = blockIdx.x;
    const int t   = threadIdx.x;
    const int n   = bid * 256 + t;

    // Prefix over preceding blocks + grand totals (512 B, L2-hot).
    u64 blo = 0, bhi = 0, tlo = 0, thi = 0;
    #pragma unroll
    for (int k = 0; k < SCAN_BLOCKS; ++k) {
        const ulonglong2 s = bsum[k];
        if (k < bid) { blo += s.x; bhi += s.y; }
        tlo += s.x; thi += s.y;
    }

    const int4 ma = mask4[(size_t)n * 2];
    const int4 mb = mask4[(size_t)n * 2 + 1];
    u64 lo = (u64)ma.x | ((u64)ma.y << 16) | ((u64)ma.z << 32) | ((u64)ma.w << 48);
    u64 hi = (u64)mb.x | ((u64)mb.y << 16) | ((u64)mb.z << 32) | ((u64)mb.w << 48);

    __shared__ u64 slo[256], shi[256];
    slo[t] = lo; shi[t] = hi;
    __syncthreads();

    for (int off = 1; off < 256; off <<= 1) {
        u64 plo = 0, phi = 0;
        if (t >= off) { plo = slo[t - off]; phi = shi[t - off]; }
        __syncthreads();
        if (t >= off) { slo[t] += plo; shi[t] += phi; }
        __syncthreads();
    }

    const u64 plo = (slo[t] - lo) + blo;   // global exclusive, packed
    const u64 phi = (shi[t] - hi) + bhi;

    const float4 s0 = score4[(size_t)n * 2];
    const float4 s1 = score4[(size_t)n * 2 + 1];
    const int   me[8] = { ma.x, ma.y, ma.z, ma.w, mb.x, mb.y, mb.z, mb.w };
    const float se[8] = { s0.x, s0.y, s0.z, s0.w, s1.x, s1.y, s1.z, s1.w };

    #pragma unroll
    for (int e = 0; e < E_NUM; ++e) {
        const u64 pk = (e < 4) ? plo : phi;
        const int r  = (int)((pk >> (16 * (e & 3))) & 0xFFFF);
        if (me[e]) {
            int2 sm; sm.x = n; sm.y = __float_as_int(se[e]);
            srcmap[(size_t)e * N_TOK + r]   = sm;
            out_tags[(size_t)e * N_TOK + r] = (float)n;
        }
    }

    // Per-expert totals.
    int cnt[8];
    #pragma unroll
    for (int e = 0; e < E_NUM; ++e) {
        const u64 pk = (e < 4) ? tlo : thi;
        cnt[e] = (int)((pk >> (16 * (e & 3))) & 0xFFFF);
    }

    if (bid == 0 && t < E_NUM) out_counts[t] = (float)cnt[t];

    // Pad fill for srcmap + tags: thread g covers index cnt_e + g (single shot).
    const int g = n;
    #pragma unroll
    for (int e = 0; e < E_NUM; ++e) {
        const int idx = cnt[e] + g;
        if (idx < N_TOK) {
            int2 sm; sm.x = -1; sm.y = 0;
            srcmap[(size_t)e * N_TOK + idx]   = sm;
            out_tags[(size_t)e * N_TOK + idx] = 0.0f;
        }
    }
}

// K3: sequential-write gather. 8192 blocks x 256 threads, 8 rows/block.
// Writes are perfectly sequential over the 256 MB output (nontemporal, bypass
// L2); reads of x (32 MB) are L3-resident and roughly monotonic per expert.
__global__ __launch_bounds__(256) void gather_kernel(
    const f32x4* __restrict__ x,          // [N, D/4]
    const int2* __restrict__ srcmap,      // [E*N]
    f32x4* __restrict__ out)              // [E*N, D/4]
{
    const int c    = threadIdx.x;
    const int row0 = blockIdx.x * ROWS_PER_BLOCK;

    #pragma unroll
    for (int i = 0; i < ROWS_PER_BLOCK; ++i) {
        const int row = row0 + i;
        const int2 sm = srcmap[row];          // uniform per block -> scalar load
        f32x4 v;
        if (sm.x >= 0) {
            const float s = __int_as_float(sm.y);
            v = x[(size_t)sm.x * D4 + c] * s;
        } else {
            v = (f32x4)0.0f;
        }
        __builtin_nontemporal_store(v, &out[(size_t)row * D4 + c]);
    }
}

extern "C" void kernel_launch(void* const* d_in, const int* in_sizes, int n_in,
                              void* d_out, int out_size, void* d_ws, size_t ws_size,
                              hipStream_t stream) {
    const float* x        = (const float*)d_in[0];
    const int*   hot_mask = (const int*)d_in[1];
    const float* score    = (const float*)d_in[2];

    float* out        = (float*)d_out;
    float* out_data   = out;                                  // [E, N, D]
    float* out_tags   = out + (size_t)E_NUM * N_TOK * D_DIM;  // [E, N]
    float* out_counts = out_tags + (size_t)E_NUM * N_TOK;     // [E]

    ulonglong2* bsum = (ulonglong2*)d_ws;                     // [32]
    int2* srcmap     = (int2*)(bsum + SCAN_BLOCKS);           // [E*N]

    reduce_kernel<<<SCAN_BLOCKS, 256, 0, stream>>>(
        (const int4*)hot_mask, bsum);

    finalize_kernel<<<SCAN_BLOCKS, 256, 0, stream>>>(
        (const int4*)hot_mask, bsum, (const float4*)score,
        srcmap, out_tags, out_counts);

    gather_kernel<<<GATHER_BLOCKS, 256, 0, stream>>>(
        (const f32x4*)x, srcmap, (f32x4*)out_data);
}

// Round 6
// 60.527 us; speedup vs baseline: 1.1616x; 1.1616x over previous
//
#include <hip/hip_runtime.h>

#define N_TOK 8192
#define D_DIM 1024
#define E_NUM 8
#define D4 (D_DIM / 4)
#define SCAN_BLOCKS 32          // N_TOK / 256

typedef unsigned long long u64;
typedef float f32x4 __attribute__((ext_vector_type(4)));

// Workspace:
//   dest[N][E]  int : global rank of token n in expert e, or -1 (256 KB)
//   counts_i[E] int
// Packing: lo = experts 0..3, hi = experts 4..7, 16-bit fields (counts <= 8192).

__device__ __forceinline__ u64 pack4(const int4 a) {
    return (u64)a.x | ((u64)a.y << 16) | ((u64)a.z << 32) | ((u64)a.w << 48);
}

// K1: single-kernel scan. 32 blocks x 256 threads, 1 token/thread.
// Every block redundantly reads the whole mask (8 MB aggregate, L2-served),
// so no inter-kernel dependency: pre-sum, grand total, and local scan in one.
__global__ __launch_bounds__(256) void scan_all_kernel(
    const int4* __restrict__ mask4,       // hot_mask as [N][2] int4
    int* __restrict__ dest,               // [N, E] (ws)
    int* __restrict__ counts_i,           // [E]    (ws)
    float* __restrict__ out_tags,         // [E, N]
    float* __restrict__ out_counts)       // [E]
{
    const int bid = blockIdx.x;
    const int t   = threadIdx.x;
    const int n   = bid * 256 + t;

    u64 pre_lo = 0, pre_hi = 0, all_lo = 0, all_hi = 0, my_lo = 0, my_hi = 0;
    for (int k = 0; k < SCAN_BLOCKS; ++k) {
        const int tok = k * 256 + t;
        const u64 lo = pack4(mask4[(size_t)tok * 2]);
        const u64 hi = pack4(mask4[(size_t)tok * 2 + 1]);
        all_lo += lo; all_hi += hi;
        if (k < bid)  { pre_lo += lo; pre_hi += hi; }
        if (k == bid) { my_lo  = lo; my_hi  = hi; }
    }

    __shared__ u64 s1[256], s2[256];

    // Reduce all -> grand totals.
    s1[t] = all_lo; s2[t] = all_hi; __syncthreads();
    for (int off = 128; off > 0; off >>= 1) {
        if (t < off) { s1[t] += s1[t + off]; s2[t] += s2[t + off]; }
        __syncthreads();
    }
    const u64 tot_lo = s1[0], tot_hi = s2[0];
    __syncthreads();

    // Reduce pre -> offset of this block.
    s1[t] = pre_lo; s2[t] = pre_hi; __syncthreads();
    for (int off = 128; off > 0; off >>= 1) {
        if (t < off) { s1[t] += s1[t + off]; s2[t] += s2[t + off]; }
        __syncthreads();
    }
    const u64 base_lo = s1[0], base_hi = s2[0];
    __syncthreads();

    // Inclusive scan of my -> within-block prefix.
    s1[t] = my_lo; s2[t] = my_hi; __syncthreads();
    for (int off = 1; off < 256; off <<= 1) {
        u64 p1 = 0, p2 = 0;
        if (t >= off) { p1 = s1[t - off]; p2 = s2[t - off]; }
        __syncthreads();
        if (t >= off) { s1[t] += p1; s2[t] += p2; }
        __syncthreads();
    }
    const u64 plo = (s1[t] - my_lo) + base_lo;   // global exclusive, packed
    const u64 phi = (s2[t] - my_hi) + base_hi;

    int d[8];
    #pragma unroll
    for (int e = 0; e < E_NUM; ++e) {
        const int sh = 16 * (e & 3);
        const int m  = (int)(((e < 4 ? my_lo : my_hi) >> sh) & 0xFFFF);
        const int r  = (int)(((e < 4 ? plo   : phi  ) >> sh) & 0xFFFF);
        d[e] = m ? r : -1;
        if (m) out_tags[(size_t)e * N_TOK + r] = (float)n;
    }

    int4* dest4 = (int4*)dest;
    int4 d0; d0.x = d[0]; d0.y = d[1]; d0.z = d[2]; d0.w = d[3];
    int4 d1; d1.x = d[4]; d1.y = d[5]; d1.z = d[6]; d1.w = d[7];
    dest4[(size_t)n * 2]     = d0;
    dest4[(size_t)n * 2 + 1] = d1;

    // Counts + tag pad fill.
    int cnt[8];
    #pragma unroll
    for (int e = 0; e < E_NUM; ++e) {
        cnt[e] = (int)(((e < 4 ? tot_lo : tot_hi) >> (16 * (e & 3))) & 0xFFFF);
    }
    if (bid == 0 && t < E_NUM) {
        counts_i[t]   = cnt[t];
        out_counts[t] = (float)cnt[t];
    }
    #pragma unroll
    for (int e = 0; e < E_NUM; ++e) {
        const int idx = cnt[e] + n;          // thread n covers pad slot cnt+n
        if (idx < N_TOK) out_tags[(size_t)e * N_TOK + idx] = 0.0f;
    }
}

// K2: fused scatter + pad-fill — Round-2 champion, single change: NT stores.
__global__ __launch_bounds__(256) void dispatch_scatter_kernel(
    const f32x4* __restrict__ x,        // [N, D/4]
    const float* __restrict__ score,    // [N, E]
    const int* __restrict__ dest,       // [N, E]
    const int* __restrict__ counts_i,   // [E]
    f32x4* __restrict__ out)            // [E*N, D/4]
{
    const int b = blockIdx.x;
    const int c = threadIdx.x;

    if (b < N_TOK) {
        const int n = b;
        const f32x4 xv = x[(size_t)n * D4 + c];
        #pragma unroll
        for (int e = 0; e < E_NUM; ++e) {
            const int r = dest[(size_t)n * E_NUM + e];   // uniform per block
            if (r >= 0) {
                const float s = score[(size_t)n * E_NUM + e];
                const f32x4 v = xv * s;
                __builtin_nontemporal_store(
                    v, &out[((size_t)e * N_TOK + r) * D4 + c]);
            }
        }
    } else {
        const int row = b - N_TOK;          // e*N + r
        const int e   = row >> 13;
        const int r   = row & (N_TOK - 1);
        if (r >= counts_i[e]) {
            const f32x4 z = (f32x4)0.0f;
            __builtin_nontemporal_store(z, &out[(size_t)row * D4 + c]);
        }
    }
}

extern "C" void kernel_launch(void* const* d_in, const int* in_sizes, int n_in,
                              void* d_out, int out_size, void* d_ws, size_t ws_size,
                              hipStream_t stream) {
    const float* x        = (const float*)d_in[0];
    const int*   hot_mask = (const int*)d_in[1];
    const float* score    = (const float*)d_in[2];

    float* out        = (float*)d_out;
    float* out_data   = out;                                  // [E, N, D]
    float* out_tags   = out + (size_t)E_NUM * N_TOK * D_DIM;  // [E, N]
    float* out_counts = out_tags + (size_t)E_NUM * N_TOK;     // [E]

    int* dest     = (int*)d_ws;                               // [N, E]
    int* counts_i = dest + (size_t)N_TOK * E_NUM;             // [E]

    scan_all_kernel<<<SCAN_BLOCKS, 256, 0, stream>>>(
        (const int4*)hot_mask, dest, counts_i, out_tags, out_counts);

    dispatch_scatter_kernel<<<N_TOK + E_NUM * N_TOK, 256, 0, stream>>>(
        (const f32x4*)x, score, dest, counts_i, (f32x4*)out_data);
}